// Round 5
// baseline (308.124 us; speedup 1.0000x reference)
//
#include <hip/hip_runtime.h>
#include <stdint.h>

#define NROWS 4
#define WCOLS 368
#define KREG  6          // ceil(368/64)
#define NWAVE 16         // fallback: tries per super-iteration
#define TMAX  256        // tries covered speculatively by eval_tries
#define KS_FLOATS 30146560   // 4*16*640*368*2
#define KS_F4     7536640    // /4
#define PER_B_F4  1884160    // 16*640*368*2/4
#define ROW_F4    184        // 368*2/4

// ---------------- Threefry-2x32, 20 rounds (JAX-compatible) ----------------
__device__ __forceinline__ void tf_block(uint32_t k0, uint32_t k1,
                                         uint32_t x0, uint32_t x1,
                                         uint32_t& o0, uint32_t& o1) {
  const uint32_t ks2 = k0 ^ k1 ^ 0x1BD11BDAu;
#define TFR(r) { x0 += x1; x1 = (x1 << (r)) | (x1 >> (32 - (r))); x1 ^= x0; }
  x0 += k0; x1 += k1;
  TFR(13) TFR(15) TFR(26) TFR(6)
  x0 += k1;  x1 += ks2 + 1u;
  TFR(17) TFR(29) TFR(16) TFR(24)
  x0 += ks2; x1 += k0 + 2u;
  TFR(13) TFR(15) TFR(26) TFR(6)
  x0 += k0;  x1 += k1 + 3u;
  TFR(17) TFR(29) TFR(16) TFR(24)
  x0 += k1;  x1 += ks2 + 4u;
  TFR(13) TFR(15) TFR(26) TFR(6)
  x0 += ks2; x1 += k0 + 5u;
#undef TFR
  o0 = x0; o1 = x1;
}

__device__ __forceinline__ float wave_sum_f(float v) {
  #pragma unroll
  for (int off = 32; off >= 1; off >>= 1) v += __shfl_xor(v, off, 64);
  return v;
}
__device__ __forceinline__ float wave_max_f(float v) {
  #pragma unroll
  for (int off = 32; off >= 1; off >>= 1) v = fmaxf(v, __shfl_xor(v, off, 64));
  return v;
}

// Phase-1 probability pipeline; byte-identical source in both kernels so the
// compiled fp sequence (and thus x[], xbar) is bit-identical across kernels.
__device__ __forceinline__ void prob_pipeline(const float* __restrict__ mask,
                                              const float* __restrict__ sampler,
                                              int b, int l,
                                              float* mk, float* x,
                                              float& xbar, float& tolv) {
  float pmv[KREG], mp[KREG], m0[KREG];
  float vmax = 0.0f;
  #pragma unroll
  for (int k = 0; k < KREG; ++k) {
    const int c = l + 64 * k;
    if (c < WCOLS) {
      const float s  = sampler[c];
      const float mv = mask[b * WCOLS + c];
      const float z  = 10.0f * s;
      const float sp = (fmaxf(z, 0.0f) + log1pf(expf(-fabsf(z)))) / 10.0f;
      mk[k] = mv; pmv[k] = sp;
      vmax = fmaxf(vmax, (1.0f - mv) * sp);
    } else { mk[k] = 1.0f; pmv[k] = 0.0f; }
  }
  const float denom = wave_max_f(vmax);

  float cnt0 = 0.0f, smp = 0.0f;
  #pragma unroll
  for (int k = 0; k < KREG; ++k) {
    const int c = l + 64 * k;
    if (c < WCOLS) {
      const float pn  = pmv[k] / denom;
      const float mpv = pn * (1.0f - mk[k]);
      const float z0  = (mk[k] == 0.0f) ? 1.0f : 0.0f;
      mp[k] = mpv; m0[k] = z0;
      cnt0 += z0; smp += mpv * z0;
    } else { mp[k] = 0.0f; m0[k] = 0.0f; }
  }
  const float count    = wave_sum_f(cnt0);
  const float sumx     = wave_sum_f(smp);
  const float sparsity = 92.0f / count;
  const float xbar_pre = sumx / count;
  const float r    = sparsity / xbar_pre;
  const float beta = (1.0f - sparsity) / (1.0f - xbar_pre);
  const bool  le   = (r <= 1.0f);

  float sx = 0.0f;
  #pragma unroll
  for (int k = 0; k < KREG; ++k) {
    const int c = l + 64 * k;
    if (c < WCOLS) {
      const float resc = le ? (mp[k] * r) : (1.0f - (1.0f - mp[k]) * beta);
      const float xv   = (m0[k] > 0.0f) ? resc : mp[k];
      x[k] = xv; sx += xv;
    } else x[k] = 0.0f;
  }
  xbar = wave_sum_f(sx) / 368.0f;
  tolv = 1e-3f + 1e-5f * fabsf(xbar);
}

// Kernel A: one wave per (row, try). Redundant scalar-chain walk to key_t
// (parallel across blocks), one draw evaluation, accept bit + ballots to ws.
__global__ __launch_bounds__(64) void eval_tries(const float* __restrict__ mask,
                                                 const float* __restrict__ sampler,
                                                 uint32_t* __restrict__ ws_acc,
                                                 uint64_t* __restrict__ ws_res,
                                                 uint32_t* __restrict__ ws_key) {
  const int b = blockIdx.x >> 8;      // / TMAX
  const int t = blockIdx.x & (TMAX - 1);
  const int l = threadIdx.x;

  float mk[KREG], x[KREG], xbar, tolv;
  prob_pipeline(mask, sampler, b, l, mk, x, xbar, tolv);

  // row key: partitionable split -> block (0, b) of key (0, 42); scalar
  uint32_t k0, k1;
  tf_block(0u, 42u, 0u, (uint32_t)b, k0, k1);
  for (int i = 0; i < t; ++i) {       // SALU chain walk, t steps
    uint32_t t0, t1; tf_block(k0, k1, 0u, 0u, t0, t1); k0 = t0; k1 = t1;
  }
  if (t == TMAX - 1) {                // store key_TMAX for fallback seeding
    uint32_t e0, e1; tf_block(k0, k1, 0u, 0u, e0, e1);
    if (l == 0) { ws_key[b * 2] = e0; ws_key[b * 2 + 1] = e1; }
  }
  uint32_t s0, s1; tf_block(k0, k1, 0u, 1u, s0, s1);   // subkey of try t

  int tot = 0;
  uint64_t bal[KREG];
  #pragma unroll
  for (int k = 0; k < KREG; ++k) {
    const int c = l + 64 * k;
    bool pred = false;
    if (c < WCOLS) {
      uint32_t y0, y1;
      tf_block(s0, s1, 0u, (uint32_t)c, y0, y1);
      const uint32_t bits = y0 ^ y1;
      const float prob = fmaxf(0.0f,
          __uint_as_float((bits >> 9) | 0x3f800000u) - 1.0f);
      pred = (x[k] > prob);
    }
    bal[k] = __ballot(pred);
    tot += (int)__popcll(bal[k]);
  }
  const bool ok = fabsf((float)tot / 368.0f - xbar) <= tolv;
  if (l == 0) {
    ws_acc[b * TMAX + t] = ok ? 1u : 0u;
    #pragma unroll
    for (int k = 0; k < KREG; ++k) ws_res[(size_t)(b * TMAX + t) * KREG + k] = bal[k];
  }
}

// Kernel B: per row, find min accepted try < TMAX and emit; else fall back to
// the 16-wave try-parallel loop for tries TMAX..1999 (exact 2000-cap semantics).
__global__ __launch_bounds__(1024) void pick_emit(const float* __restrict__ mask,
                                                  const float* __restrict__ sampler,
                                                  const uint32_t* __restrict__ ws_acc,
                                                  const uint64_t* __restrict__ ws_res,
                                                  const uint32_t* __restrict__ ws_key,
                                                  float* __restrict__ new_mask,
                                                  float* __restrict__ fpm) {
  const int b = blockIdx.x;
  const int w = threadIdx.x >> 6;
  const int l = threadIdx.x & 63;

  __shared__ int s_tstar;
  __shared__ uint32_t keybuf[2][NWAVE][2];
  __shared__ int acc_ls[2][NWAVE];

  float mk[KREG], x[KREG], xbar, tolv;
  prob_pipeline(mask, sampler, b, l, mk, x, xbar, tolv);

  if (w == 0) {
    int tstar = -1;
    #pragma unroll
    for (int chunk = 0; chunk < TMAX / 64; ++chunk) {
      const uint32_t f = ws_acc[b * TMAX + chunk * 64 + l];
      const uint64_t m = __ballot(f != 0u);
      if (tstar < 0 && m) tstar = chunk * 64 + (int)(__ffsll((long long)m) - 1);
    }
    if (l == 0) s_tstar = tstar;
  }
  __syncthreads();
  const int tstar = s_tstar;

  if (tstar >= 0) {
    if (w == 0) {
      #pragma unroll
      for (int k = 0; k < KREG; ++k) {
        const int c = l + 64 * k;
        if (c < WCOLS) {
          const uint64_t bal = ws_res[(size_t)(b * TMAX + tstar) * KREG + k];
          const float acq = ((bal >> l) & 1ull) ? 1.0f : 0.0f;
          new_mask[b * WCOLS + c] = mk[k] + acq;
          fpm[b * WCOLS + c]      = x[k];
        }
      }
    }
    return;
  }

  // ---- fallback: tries TMAX..1999, seeded from stored key_TMAX ----
  if (w == 0) {
    uint32_t c0 = ws_key[b * 2], c1 = ws_key[b * 2 + 1];
    for (int i = 0; i < NWAVE; ++i) {
      if (l == 0) { keybuf[0][i][0] = c0; keybuf[0][i][1] = c1; }
      uint32_t t0, t1; tf_block(c0, c1, 0u, 0u, t0, t1); c0 = t0; c1 = t1;
    }
  }
  __syncthreads();

  uint32_t res = 0;
  int winner = -1;
  int cur = 0;
  for (int it = 0; it < (2000 - TMAX) / NWAVE; ++it) {
    const uint32_t k0 = keybuf[cur][w][0];
    const uint32_t k1 = keybuf[cur][w][1];

    if (w == (it & (NWAVE - 1))) {
      uint32_t c0 = keybuf[cur][NWAVE - 1][0];
      uint32_t c1 = keybuf[cur][NWAVE - 1][1];
      for (int i = 0; i < NWAVE; ++i) {
        uint32_t t0, t1; tf_block(c0, c1, 0u, 0u, t0, t1); c0 = t0; c1 = t1;
        if (l == 0) { keybuf[cur ^ 1][i][0] = c0; keybuf[cur ^ 1][i][1] = c1; }
      }
    }

    uint32_t s0, s1; tf_block(k0, k1, 0u, 1u, s0, s1);

    res = 0;
    int tot = 0;
    #pragma unroll
    for (int k = 0; k < KREG; ++k) {
      const int c = l + 64 * k;
      bool pred = false;
      if (c < WCOLS) {
        uint32_t y0, y1;
        tf_block(s0, s1, 0u, (uint32_t)c, y0, y1);
        const uint32_t bits = y0 ^ y1;
        const float prob = fmaxf(0.0f,
            __uint_as_float((bits >> 9) | 0x3f800000u) - 1.0f);
        pred = (x[k] > prob);
        if (pred) res |= (1u << k);
      }
      tot += (int)__popcll(__ballot(pred));
    }
    const bool okw = fabsf((float)tot / 368.0f - xbar) <= tolv;
    if (l == 0) acc_ls[cur][w] = okw ? 1 : 0;
    __syncthreads();
    int win = -1;
    #pragma unroll
    for (int i = 0; i < NWAVE; ++i) {
      if (win < 0 && acc_ls[cur][i]) win = i;
    }
    if (win >= 0) { winner = win; break; }
    cur ^= 1;
  }
  if (winner < 0) winner = NWAVE - 1;   // 2000-try cap: keep last result

  if (w == winner) {
    #pragma unroll
    for (int k = 0; k < KREG; ++k) {
      const int c = l + 64 * k;
      if (c < WCOLS) {
        const float acq = ((res >> k) & 1u) ? 1.0f : 0.0f;
        new_mask[b * WCOLS + c] = mk[k] + acq;
        fpm[b * WCOLS + c]      = x[k];
      }
    }
  }
}

// Elementwise masked kspace. Sign-fix in ref == "+0 wherever mask==0".
__global__ __launch_bounds__(256) void apply_mask(const float4* __restrict__ ks,
                                                  const float* __restrict__ nm,
                                                  float4* __restrict__ out) {
  const int q = blockIdx.x * 256 + threadIdx.x;   // grid covers KS_F4 exactly
  const int b  = q / PER_B_F4;
  const int qw = q % ROW_F4;
  const int w0 = qw * 2;
  const float mA = nm[b * WCOLS + w0];
  const float mB = nm[b * WCOLS + w0 + 1];
  const float4 v = ks[q];
  float4 o;
  o.x = (mA != 0.0f) ? mA * v.x : 0.0f;
  o.y = (mA != 0.0f) ? mA * v.y : 0.0f;
  o.z = (mB != 0.0f) ? mB * v.z : 0.0f;
  o.w = (mB != 0.0f) ? mB * v.w : 0.0f;
  out[q] = o;
}

extern "C" void kernel_launch(void* const* d_in, const int* in_sizes, int n_in,
                              void* d_out, int out_size, void* d_ws, size_t ws_size,
                              hipStream_t stream) {
  const float* mask    = (const float*)d_in[0];
  const float* kspace  = (const float*)d_in[1];
  const float* sampler = (const float*)d_in[2];

  float* out      = (float*)d_out;
  float* new_mask = out;                              // B*W = 1472
  float* mkspace  = out + NROWS * WCOLS;              // 30146560
  float* fpm      = out + NROWS * WCOLS + KS_FLOATS;  // 1472

  uint32_t* ws_acc = (uint32_t*)d_ws;                                   // 4*256*4 B
  uint64_t* ws_res = (uint64_t*)((char*)d_ws + 4096);                   // 4*256*6*8 B
  uint32_t* ws_key = (uint32_t*)((char*)d_ws + 4096 + 49152);           // 4*2*4 B

  eval_tries<<<NROWS * TMAX, 64, 0, stream>>>(mask, sampler, ws_acc, ws_res, ws_key);
  pick_emit<<<NROWS, 1024, 0, stream>>>(mask, sampler, ws_acc, ws_res, ws_key,
                                        new_mask, fpm);
  apply_mask<<<KS_F4 / 256, 256, 0, stream>>>((const float4*)kspace, new_mask,
                                              (float4*)mkspace);
}

// Round 6
// 246.467 us; speedup vs baseline: 1.2502x; 1.2502x over previous
//
#include <hip/hip_runtime.h>
#include <stdint.h>

#define NROWS 4
#define WCOLS 368
#define KREG  6          // ceil(368/64)
#define NWAVE 16         // tries evaluated per super-iteration
#define KS_FLOATS 30146560   // 4*16*640*368*2
#define KS_F4     7536640    // /4
#define PER_B_F4  1884160    // 16*640*368*2/4
#define ROW_F4    184        // 368*2/4

// ---------------- Threefry-2x32, 20 rounds (JAX-compatible) ----------------
// Rotates via __builtin_rotateleft32 -> single v_alignbit_b32: dependent
// depth per round drops from ~4-5 ops to ~2 (chain latency ~2.5x lower).
__device__ __forceinline__ void tf_block(uint32_t k0, uint32_t k1,
                                         uint32_t x0, uint32_t x1,
                                         uint32_t& o0, uint32_t& o1) {
  const uint32_t ks2 = k0 ^ k1 ^ 0x1BD11BDAu;
#define TFR(r) { x0 += x1; x1 = __builtin_rotateleft32(x1, (r)); x1 ^= x0; }
  x0 += k0; x1 += k1;
  TFR(13) TFR(15) TFR(26) TFR(6)
  x0 += k1;  x1 += ks2 + 1u;
  TFR(17) TFR(29) TFR(16) TFR(24)
  x0 += ks2; x1 += k0 + 2u;
  TFR(13) TFR(15) TFR(26) TFR(6)
  x0 += k0;  x1 += k1 + 3u;
  TFR(17) TFR(29) TFR(16) TFR(24)
  x0 += k1;  x1 += ks2 + 4u;
  TFR(13) TFR(15) TFR(26) TFR(6)
  x0 += ks2; x1 += k0 + 5u;
#undef TFR
  o0 = x0; o1 = x1;
}

__device__ __forceinline__ float wave_sum_f(float v) {
  #pragma unroll
  for (int off = 32; off >= 1; off >>= 1) v += __shfl_xor(v, off, 64);
  return v;
}
__device__ __forceinline__ float wave_max_f(float v) {
  #pragma unroll
  for (int off = 32; off >= 1; off >>= 1) v = fmaxf(v, __shfl_xor(v, off, 64));
  return v;
}

// One 1024-thread block per batch row. 16 waves evaluate 16 consecutive tries
// concurrently. The serial Threefry key chain (the real latency bound) is
// extended 16 steps/iter by a rotating duty wave into a double-buffered LDS
// key table; accept winner found via one LDS read + ballot. 1 barrier/iter.
__global__ __launch_bounds__(1024) void sample_rows(const float* __restrict__ mask,
                                                    const float* __restrict__ sampler,
                                                    float* __restrict__ new_mask,
                                                    float* __restrict__ fpm) {
  const int b = blockIdx.x;
  const int w = threadIdx.x >> 6;   // wave id 0..15 == try offset within group
  const int l = threadIdx.x & 63;

  __shared__ uint32_t keybuf[2][NWAVE][2];  // chain keys for tries base..base+15
  __shared__ int acc_ls[2][NWAVE];          // double-buffered accept flags

  // ---- Phase 1: probability pipeline (redundant per wave; identical fp ops
  // across waves -> identical x[], xbar in every wave) ----
  float mk[KREG], pmv[KREG], mp[KREG], m0[KREG], x[KREG];

  float vmax = 0.0f;
  #pragma unroll
  for (int k = 0; k < KREG; ++k) {
    const int c = l + 64 * k;
    if (c < WCOLS) {
      const float s  = sampler[c];
      const float mv = mask[b * WCOLS + c];
      const float z  = 10.0f * s;
      const float sp = (fmaxf(z, 0.0f) + log1pf(expf(-fabsf(z)))) / 10.0f;
      mk[k] = mv; pmv[k] = sp;
      vmax = fmaxf(vmax, (1.0f - mv) * sp);
    } else { mk[k] = 1.0f; pmv[k] = 0.0f; }
  }
  const float denom = wave_max_f(vmax);

  float cnt0 = 0.0f, smp = 0.0f;
  #pragma unroll
  for (int k = 0; k < KREG; ++k) {
    const int c = l + 64 * k;
    if (c < WCOLS) {
      const float pn  = pmv[k] / denom;
      const float mpv = pn * (1.0f - mk[k]);
      const float z0  = (mk[k] == 0.0f) ? 1.0f : 0.0f;
      mp[k] = mpv; m0[k] = z0;
      cnt0 += z0; smp += mpv * z0;
    } else { mp[k] = 0.0f; m0[k] = 0.0f; }
  }
  const float count    = wave_sum_f(cnt0);
  const float sumx     = wave_sum_f(smp);
  const float sparsity = 92.0f / count;
  const float xbar_pre = sumx / count;
  const float r    = sparsity / xbar_pre;
  const float beta = (1.0f - sparsity) / (1.0f - xbar_pre);
  const bool  le   = (r <= 1.0f);

  float sx = 0.0f;
  #pragma unroll
  for (int k = 0; k < KREG; ++k) {
    const int c = l + 64 * k;
    if (c < WCOLS) {
      const float resc = le ? (mp[k] * r) : (1.0f - (1.0f - mp[k]) * beta);
      const float xv   = (m0[k] > 0.0f) ? resc : mp[k];
      x[k] = xv; sx += xv;
    } else x[k] = 0.0f;
  }
  const float xbar = wave_sum_f(sx) / 368.0f;
  const float tolv = 1e-3f + 1e-5f * fabsf(xbar);

  // ---- Phase 2: try-parallel rejection sampling ----
  // row key: partitionable split -> block (0, b) of key (0, 42)
  uint32_t rk0, rk1;
  tf_block(0u, 42u, 0u, (uint32_t)b, rk0, rk1);

  // prologue: wave 0 fills keybuf[0][i] = key_i for tries 0..15
  if (w == 0) {
    uint32_t c0 = rk0, c1 = rk1;
    for (int i = 0; i < NWAVE; ++i) {
      if (l == 0) { keybuf[0][i][0] = c0; keybuf[0][i][1] = c1; }
      uint32_t t0, t1; tf_block(c0, c1, 0u, 0u, t0, t1); c0 = t0; c1 = t1;
    }
  }
  __syncthreads();

  uint32_t res = 0;
  int winner = -1;
  int cur = 0;
  for (int it = 0; it < 125; ++it) {           // 125*16 = 2000-try cap
    const uint32_t k0 = keybuf[cur][w][0];
    const uint32_t k1 = keybuf[cur][w][1];

    // rotating duty wave extends the chain 16 steps into the other buffer;
    // with 1-instr rotates this is ~3.2k cy, the per-iteration critical path
    if (w == (it & (NWAVE - 1))) {
      uint32_t c0 = keybuf[cur][NWAVE - 1][0];
      uint32_t c1 = keybuf[cur][NWAVE - 1][1];
      for (int i = 0; i < NWAVE; ++i) {
        uint32_t t0, t1; tf_block(c0, c1, 0u, 0u, t0, t1); c0 = t0; c1 = t1;
        if (l == 0) { keybuf[cur ^ 1][i][0] = c0; keybuf[cur ^ 1][i][1] = c1; }
      }
    }

    // subkey for this wave's try = keys_out[1] of split(key)
    uint32_t s0, s1; tf_block(k0, k1, 0u, 1u, s0, s1);

    res = 0;
    int tot = 0;
    #pragma unroll
    for (int k = 0; k < KREG; ++k) {
      const int c = l + 64 * k;
      bool pred = false;
      if (c < WCOLS) {
        uint32_t y0, y1;
        tf_block(s0, s1, 0u, (uint32_t)c, y0, y1);
        const uint32_t bits = y0 ^ y1;                       // partitionable fold
        const float prob = fmaxf(0.0f,
            __uint_as_float((bits >> 9) | 0x3f800000u) - 1.0f);
        pred = (x[k] > prob);
        if (pred) res |= (1u << k);
      }
      tot += (int)__popcll(__ballot(pred));                  // uniform count
    }
    const bool okw = fabsf((float)tot / 368.0f - xbar) <= tolv;  // uniform
    if (l == 0) acc_ls[cur][w] = okw ? 1 : 0;
    __syncthreads();   // flags in acc_ls[cur] + keys in keybuf[cur^1] ready

    // winner = min accepted wave: one broadcast LDS read + ballot
    const int fl = acc_ls[cur][l & (NWAVE - 1)];
    const uint64_t am = __ballot((l < NWAVE) && (fl != 0));
    if (am) { winner = (int)(__ffsll((long long)am) - 1); break; }
    cur ^= 1;
    // safe without 2nd barrier: slots just read are rewritten only after the
    // NEXT barrier (2-deep buffering)
  }
  if (winner < 0) winner = NWAVE - 1;   // 2000-try cap: keep last result (try 1999)

  if (w == winner) {
    #pragma unroll
    for (int k = 0; k < KREG; ++k) {
      const int c = l + 64 * k;
      if (c < WCOLS) {
        const float acq = ((res >> k) & 1u) ? 1.0f : 0.0f;
        new_mask[b * WCOLS + c] = mk[k] + acq;
        fpm[b * WCOLS + c]      = x[k];
      }
    }
  }
}

// Elementwise masked kspace. Sign-fix in ref == "+0 wherever mask==0".
__global__ __launch_bounds__(256) void apply_mask(const float4* __restrict__ ks,
                                                  const float* __restrict__ nm,
                                                  float4* __restrict__ out) {
  const int q = blockIdx.x * 256 + threadIdx.x;   // grid covers KS_F4 exactly
  const int b  = q / PER_B_F4;
  const int qw = q % ROW_F4;
  const int w0 = qw * 2;
  const float mA = nm[b * WCOLS + w0];
  const float mB = nm[b * WCOLS + w0 + 1];
  const float4 v = ks[q];
  float4 o;
  o.x = (mA != 0.0f) ? mA * v.x : 0.0f;
  o.y = (mA != 0.0f) ? mA * v.y : 0.0f;
  o.z = (mB != 0.0f) ? mB * v.z : 0.0f;
  o.w = (mB != 0.0f) ? mB * v.w : 0.0f;
  out[q] = o;
}

extern "C" void kernel_launch(void* const* d_in, const int* in_sizes, int n_in,
                              void* d_out, int out_size, void* d_ws, size_t ws_size,
                              hipStream_t stream) {
  const float* mask    = (const float*)d_in[0];
  const float* kspace  = (const float*)d_in[1];
  const float* sampler = (const float*)d_in[2];

  float* out      = (float*)d_out;
  float* new_mask = out;                              // B*W = 1472
  float* mkspace  = out + NROWS * WCOLS;              // 30146560
  float* fpm      = out + NROWS * WCOLS + KS_FLOATS;  // 1472

  sample_rows<<<NROWS, 1024, 0, stream>>>(mask, sampler, new_mask, fpm);
  apply_mask<<<KS_F4 / 256, 256, 0, stream>>>((const float4*)kspace, new_mask,
                                              (float4*)mkspace);
}